// Round 1
// baseline (165.460 us; speedup 1.0000x reference)
//
#include <hip/hip_runtime.h>

// out[b, (s*3+c), h, w] = in[b, c, (h - j) & 511, (w - i) & 511]
// where s = (i+2)*5 + (j+2), i,j in [-2,2].
// Input:  [8, 3, 512, 512] f32  (25 MB, L2/L3-resident)
// Output: [8, 75, 512, 512] f32 (629 MB) -> write-BW-bound.

#define TOTAL_F4 39321600LL  // 8*75*512*512 / 4

__global__ __launch_bounds__(256) void roll_stack_kernel(
    const float* __restrict__ in, float* __restrict__ out) {
    long long o4 = (long long)blockIdx.x * blockDim.x + threadIdx.x;
    if (o4 >= TOTAL_F4) return;

    int w4 = (int)(o4 & 127);          // 128 float4 per row of 512
    long long rest = o4 >> 7;
    int h = (int)(rest & 511);
    rest >>= 9;
    int ch = (int)(rest % 75);         // channel within [0,75)
    int b  = (int)(rest / 75);

    int s = ch / 3;                    // shift index 0..24
    int c = ch - s * 3;                // original channel 0..2
    int i = s / 5 - 2;                 // W shift
    int j = (s - (s / 5) * 5) - 2;     // H shift

    int src_h = (h - j + 512) & 511;
    const float* __restrict__ row =
        in + (((long long)(b * 3 + c) * 512 + src_h) << 9);

    int w0 = w4 << 2;
    float4 v;
    v.x = row[(w0     - i + 512) & 511];
    v.y = row[(w0 + 1 - i + 512) & 511];
    v.z = row[(w0 + 2 - i + 512) & 511];
    v.w = row[(w0 + 3 - i + 512) & 511];

    reinterpret_cast<float4*>(out)[o4] = v;
}

extern "C" void kernel_launch(void* const* d_in, const int* in_sizes, int n_in,
                              void* d_out, int out_size, void* d_ws, size_t ws_size,
                              hipStream_t stream) {
    const float* in = (const float*)d_in[0];
    float* out = (float*)d_out;
    const int block = 256;
    const long long nthreads = TOTAL_F4;
    const int grid = (int)((nthreads + block - 1) / block);  // 153600
    roll_stack_kernel<<<grid, block, 0, stream>>>(in, out);
}

// Round 2
// 100.930 us; speedup vs baseline: 1.6393x; 1.6393x over previous
//
#include <hip/hip_runtime.h>

// out[b, (s*3+c), h, w] = in[b, c, (h - j) & 511, (w - i) & 511]
// where s = (i+2)*5 + (j+2), i,j in [-2,2].
// Input:  [8, 3, 512, 512] f32  (25 MB, should stay L2-resident)
// Output: [8, 75, 512, 512] f32 (629 MB) -> write-BW-bound.
//
// Round 1 -> 2 changes:
//  * single unaligned (4B-aligned) float4 load for the 126/128 interior
//    positions instead of 4 scalar loads (wrap only at w4==0 / w4==127)
//  * nontemporal stores so the 629 MB output stream doesn't evict the
//    input planes from the 4 MiB per-XCD L2 (input is re-read 25x)

#define TOTAL_F4 39321600LL  // 8*75*512*512 / 4

typedef float vfloat4 __attribute__((ext_vector_type(4)));
typedef float vfloat4u __attribute__((ext_vector_type(4), aligned(4)));

__global__ __launch_bounds__(256) void roll_stack_kernel(
    const float* __restrict__ in, float* __restrict__ out) {
    long long o4 = (long long)blockIdx.x * blockDim.x + threadIdx.x;
    if (o4 >= TOTAL_F4) return;

    int w4 = (int)(o4 & 127);          // 128 float4 per row of 512
    long long rest = o4 >> 7;
    int h = (int)(rest & 511);
    rest >>= 9;
    int ch = (int)(rest % 75);         // channel within [0,75)
    int b  = (int)(rest / 75);

    int s = ch / 3;                    // shift index 0..24
    int c = ch - s * 3;                // original channel 0..2
    int i = s / 5 - 2;                 // W shift
    int j = (s - (s / 5) * 5) - 2;     // H shift

    int src_h = (h - j + 512) & 511;
    const float* __restrict__ row =
        in + (((long long)(b * 3 + c) * 512 + src_h) << 9);

    int w0 = w4 << 2;
    bool wrap = (i > 0 && w4 == 0) || (i < 0 && w4 == 127);

    vfloat4 v;
    if (!wrap) {
        // interior: w0-i .. w0-i+3 all within [0,511]
        v = *reinterpret_cast<const vfloat4u*>(row + (w0 - i));
    } else {
        v.x = row[(w0     - i + 512) & 511];
        v.y = row[(w0 + 1 - i + 512) & 511];
        v.z = row[(w0 + 2 - i + 512) & 511];
        v.w = row[(w0 + 3 - i + 512) & 511];
    }

    __builtin_nontemporal_store(v, reinterpret_cast<vfloat4*>(out) + o4);
}

extern "C" void kernel_launch(void* const* d_in, const int* in_sizes, int n_in,
                              void* d_out, int out_size, void* d_ws, size_t ws_size,
                              hipStream_t stream) {
    const float* in = (const float*)d_in[0];
    float* out = (float*)d_out;
    const int block = 256;
    const long long nthreads = TOTAL_F4;
    const int grid = (int)((nthreads + block - 1) / block);  // 153600
    roll_stack_kernel<<<grid, block, 0, stream>>>(in, out);
}